// Round 1
// 540.201 us; speedup vs baseline: 1.1187x; 1.1187x over previous
//
#include <hip/hip_runtime.h>
#include <hip/hip_bf16.h>

#define BB 8
#define TT 8192
#define HH 16
#define HDIM 64
#define DDIM 1024
#define NS 16           /* splits per (b,h) */
#define TSPLIT 512      /* positions per split */
#define KS1 16          /* split-K for qkv GEMV (1024/64 rows each) */
#define KS2 32          /* split-K for proj GEMV (1024/32 rows each) */

// idx may arrive as int64 or int32; detect by high-word probe (values < 8192).
__device__ __forceinline__ int load_idx(const int* __restrict__ idx, int b) {
  const bool wide = (idx[1] == 0) && (idx[3] == 0) && (idx[5] == 0) && (idx[7] == 0);
  int v = wide ? idx[2 * b] : idx[b];
  return min(max(v, 0), TT - 1);   // defensive clamp: never OOB
}

// ---------------------------------------------------------------------------
// Kernel A1: split-K partial of qkv = x @ W_attn.
// grid = b(8) * jchunk(3) * ks(KS1) = 384 blocks, 256 threads.
// Each thread computes 4 adjacent outputs (float4 weight loads, fully
// coalesced: one wave reads 1 KB contiguous per dd row). K-slice = 64 rows.
// ---------------------------------------------------------------------------
__global__ __launch_bounds__(256) void qkv_split_kernel(
    const float* __restrict__ x, const float* __restrict__ W,
    float* __restrict__ part)
{
  const int bid = blockIdx.x;
  const int ks = bid & (KS1 - 1);
  const int jc = (bid >> 4) % 3;
  const int b  = bid / (3 * KS1);
  const int tid = threadIdx.x;

  __shared__ float x_s[64];
  if (tid < 64) x_s[tid] = x[b * DDIM + ks * 64 + tid];
  __syncthreads();

  const int j0 = jc * 1024 + tid * 4;
  const float* wp = W + (size_t)(ks * 64) * 3072 + j0;
  float4 acc = {0.f, 0.f, 0.f, 0.f};
  #pragma unroll 8
  for (int dd = 0; dd < 64; ++dd) {
    float4 w4 = *(const float4*)(wp + (size_t)dd * 3072);
    const float xv = x_s[dd];
    acc.x += xv * w4.x; acc.y += xv * w4.y;
    acc.z += xv * w4.z; acc.w += xv * w4.w;
  }
  *(float4*)(part + (size_t)ks * (BB * 3072) + b * 3072 + j0) = acc;
}

// ---------------------------------------------------------------------------
// Kernel A2: reduce KS1 partials + bias; route to q_ws/kstep/vstep + out.
// 96 blocks x 256 (24576 outputs). All partials are L2/L3-resident.
// ---------------------------------------------------------------------------
__global__ __launch_bounds__(256) void qkv_reduce_kernel(
    const float* __restrict__ part, const float* __restrict__ bias,
    float* __restrict__ q_ws, float* __restrict__ kstep_ws,
    float* __restrict__ vstep_ws, float* __restrict__ out)
{
  const int g = blockIdx.x * 256 + threadIdx.x;   // 0..24575
  const int b = g / 3072;
  const int j = g % 3072;
  float acc = bias[j];
  #pragma unroll
  for (int ks = 0; ks < KS1; ++ks) acc += part[(size_t)ks * (BB * 3072) + g];

  if (j < 1024) {
    q_ws[b * DDIM + j] = acc * 0.125f;  // 1/sqrt(64)
  } else if (j < 2048) {
    const int jj = j - 1024;
    kstep_ws[b * DDIM + jj] = acc;
    out[8192 + b * DDIM + jj] = acc;    // output 1: k_step (fp32)
  } else {
    const int jj = j - 2048;
    vstep_ws[b * DDIM + jj] = acc;
    out[16384 + b * DDIM + jj] = acc;   // output 2: v_step (fp32)
  }
}

// ---------------------------------------------------------------------------
// Kernel B: flash-decode partial. Block = (b, h, split s) over TSPLIT=512
// positions for ONE head. Substitutes k_step/v_step at t == idx[b] via
// branchless pointer select; masks t > idx[b]. 4 barriers total (wave-level
// shuffle reductions). Writes per-(b,h,s): m, l, o[64] (unnormalized).
// ---------------------------------------------------------------------------
__global__ __launch_bounds__(256) void attn_partial_kernel(
    const float* __restrict__ past_k, const float* __restrict__ past_v,
    const int* __restrict__ idx,
    const float* __restrict__ q_ws, const float* __restrict__ kstep_ws,
    const float* __restrict__ vstep_ws,
    float* __restrict__ part_m, float* __restrict__ part_l,
    float* __restrict__ part_o)
{
  const int tid = threadIdx.x;
  const int s  = blockIdx.x & (NS - 1);
  const int h  = (blockIdx.x >> 4) & (HH - 1);
  const int b  = blockIdx.x >> 8;
  const int idxb = load_idx(idx, b);
  const int t0 = s * TSPLIT;
  const int bhs = (b * HH + h) * NS + s;

  if (t0 > idxb) {   // whole split masked (uniform branch, before any barrier)
    if (tid == 0) { part_m[bhs] = -1e30f; part_l[bhs] = 0.f; }
    return;
  }
  const int nvalid = min(TSPLIT, idxb - t0 + 1);

  __shared__ float q_s[HDIM];
  __shared__ float p_s[TSPLIT];
  __shared__ float redm[8], redl[8];
  __shared__ float o_s[16 * HDIM];

  if (tid < HDIM) q_s[tid] = q_ws[b * DDIM + h * HDIM + tid];
  __syncthreads();                                   // barrier 1

  // ---- phase 1: scores, 2 positions per thread ----
  const float* Kb = past_k + (((size_t)b * TT + t0) * HH + h) * HDIM;
  const float* krow_step = kstep_ws + b * DDIM + h * HDIM;
  float sc[2];
  #pragma unroll
  for (int i = 0; i < 2; ++i) {
    const int tl = tid + i * 256;
    float v = -1e30f;
    if (tl < nvalid) {
      const float* kr = (t0 + tl == idxb) ? krow_step
                                          : (Kb + (size_t)tl * (HH * HDIM));
      const float4* k4 = (const float4*)kr;
      float a0 = 0.f, a1 = 0.f, a2 = 0.f, a3 = 0.f;
      #pragma unroll
      for (int seg = 0; seg < 16; ++seg) {
        float4 u = k4[seg];
        a0 += q_s[seg * 4 + 0] * u.x;
        a1 += q_s[seg * 4 + 1] * u.y;
        a2 += q_s[seg * 4 + 2] * u.z;
        a3 += q_s[seg * 4 + 3] * u.w;
      }
      v = (a0 + a1) + (a2 + a3);
    }
    sc[i] = v;
  }

  // ---- phase 2: block max (wave shuffle + 4-slot LDS), exp, block sum ----
  float lmax = fmaxf(sc[0], sc[1]);
  #pragma unroll
  for (int m = 32; m > 0; m >>= 1) lmax = fmaxf(lmax, __shfl_xor(lmax, m, 64));
  if ((tid & 63) == 0) redm[tid >> 6] = lmax;
  __syncthreads();                                   // barrier 2
  const float mh = fmaxf(fmaxf(redm[0], redm[1]), fmaxf(redm[2], redm[3]));

  float lsum = 0.f;
  #pragma unroll
  for (int i = 0; i < 2; ++i) {
    float p = __expf(sc[i] - mh);   // masked rows: exp(-1e30 - mh) -> 0
    p_s[tid + i * 256] = p;
    lsum += p;
  }
  #pragma unroll
  for (int m = 32; m > 0; m >>= 1) lsum += __shfl_xor(lsum, m, 64);
  if ((tid & 63) == 0) redl[tid >> 6] = lsum;
  __syncthreads();                                   // barrier 3 (covers p_s)
  if (tid == 0) {
    part_m[bhs] = mh;
    part_l[bhs] = redl[0] + redl[1] + redl[2] + redl[3];
  }

  // ---- phase 3: o[d] = sum_t p[t]*V[t][d]; thread = (t-stripe, d-quad) ----
  const int tg = tid >> 4;          // 0..15  t-stripe
  const int d0 = (tid & 15) * 4;    // 0..60  d-quad
  const float* Vb = past_v + (((size_t)b * TT + t0) * HH + h) * HDIM + d0;
  const float* vrow_step = vstep_ws + b * DDIM + h * HDIM + d0;
  float a0 = 0.f, a1 = 0.f, a2 = 0.f, a3 = 0.f;
  for (int tl = tg; tl < nvalid; tl += 16) {
    const float p = p_s[tl];
    const float4 u = *(const float4*)((t0 + tl == idxb)
                                          ? vrow_step
                                          : (Vb + (size_t)tl * (HH * HDIM)));
    a0 += p * u.x; a1 += p * u.y; a2 += p * u.z; a3 += p * u.w;
  }
  o_s[tg * HDIM + d0 + 0] = a0;
  o_s[tg * HDIM + d0 + 1] = a1;
  o_s[tg * HDIM + d0 + 2] = a2;
  o_s[tg * HDIM + d0 + 3] = a3;
  __syncthreads();                                   // barrier 4
  if (tid < HDIM) {
    float acc = 0.f;
    #pragma unroll
    for (int g2 = 0; g2 < 16; ++g2) acc += o_s[g2 * HDIM + tid];
    part_o[(size_t)bhs * HDIM + tid] = acc;
  }
}

// ---------------------------------------------------------------------------
// Kernel C: combine NS split partials per (b,h). 128 blocks x 64 lanes.
// ---------------------------------------------------------------------------
__global__ __launch_bounds__(64) void attn_combine_kernel(
    const float* __restrict__ part_m, const float* __restrict__ part_l,
    const float* __restrict__ part_o, float* __restrict__ y_ws)
{
  const int bh = blockIdx.x;
  const int lane = threadIdx.x;

  float m[NS], l[NS];
  float M = -1e30f;
  #pragma unroll
  for (int s = 0; s < NS; ++s) {
    m[s] = part_m[bh * NS + s];
    l[s] = part_l[bh * NS + s];
    M = fmaxf(M, m[s]);
  }
  float L = 0.f, acc = 0.f;
  #pragma unroll
  for (int s = 0; s < NS; ++s) {
    float w = (l[s] > 0.f) ? __expf(m[s] - M) : 0.f;
    if (w > 0.f) {    // skip inactive splits: their part_o is poison
      L += l[s] * w;
      acc += w * part_o[(size_t)(bh * NS + s) * HDIM + lane];
    }
  }
  y_ws[bh * HDIM + lane] = (L > 0.f) ? (acc / L) : 0.f;
}

// ---------------------------------------------------------------------------
// Kernel D1: split-K partial of out_y = y @ W_proj.
// grid = b(8) * ks(KS2) = 256 blocks, 256 threads; thread = 4 outputs.
// ---------------------------------------------------------------------------
__global__ __launch_bounds__(256) void proj_split_kernel(
    const float* __restrict__ y_ws, const float* __restrict__ W,
    float* __restrict__ part)
{
  const int bid = blockIdx.x;
  const int ks = bid & (KS2 - 1);
  const int b  = bid >> 5;
  const int tid = threadIdx.x;

  __shared__ float y_s[32];
  if (tid < 32) y_s[tid] = y_ws[b * DDIM + ks * 32 + tid];
  __syncthreads();

  const int j0 = tid * 4;
  const float* wp = W + (size_t)(ks * 32) * DDIM + j0;
  float4 acc = {0.f, 0.f, 0.f, 0.f};
  #pragma unroll 8
  for (int dd = 0; dd < 32; ++dd) {
    float4 w4 = *(const float4*)(wp + (size_t)dd * DDIM);
    const float yv = y_s[dd];
    acc.x += yv * w4.x; acc.y += yv * w4.y;
    acc.z += yv * w4.z; acc.w += yv * w4.w;
  }
  *(float4*)(part + (size_t)ks * (BB * DDIM) + b * DDIM + j0) = acc;
}

// ---------------------------------------------------------------------------
// Kernel D2: reduce KS2 proj partials + bias -> out[0..8192).
// 32 blocks x 256 (8192 outputs); partials are L2-resident.
// ---------------------------------------------------------------------------
__global__ __launch_bounds__(256) void proj_reduce_kernel(
    const float* __restrict__ part, const float* __restrict__ bias,
    float* __restrict__ out)
{
  const int g = blockIdx.x * 256 + threadIdx.x;   // 0..8191
  const int j = g & 1023;
  float acc = bias[j];
  #pragma unroll
  for (int ks = 0; ks < KS2; ++ks) acc += part[(size_t)ks * (BB * DDIM) + g];
  out[g] = acc;   // output 0: y (fp32)
}

// ---------------------------------------------------------------------------
// Workspace layout (floats): total = 823296 floats = 3.29 MB
//   q_ws      [     0 ..   8192)
//   kstep_ws  [  8192 ..  16384)
//   vstep_ws  [ 16384 ..  24576)
//   y_ws      [ 24576 ..  32768)
//   part_m    [ 32768 ..  34816)   B*H*NS = 2048
//   part_l    [ 34816 ..  36864)
//   part_o    [ 36864 .. 167936)   B*H*NS*HDIM = 131072
//   qkv_part  [167936 .. 561152)   KS1 * 24576 = 393216
//   proj_part [561152 .. 823296)   KS2 * 8192  = 262144
// ---------------------------------------------------------------------------
extern "C" void kernel_launch(void* const* d_in, const int* in_sizes, int n_in,
                              void* d_out, int out_size, void* d_ws, size_t ws_size,
                              hipStream_t stream) {
  const float* x      = (const float*)d_in[0];
  const float* past_k = (const float*)d_in[1];
  const float* past_v = (const float*)d_in[2];
  const int*   idx    = (const int*)  d_in[3];
  const float* W_attn = (const float*)d_in[4];
  const float* b_attn = (const float*)d_in[5];
  const float* W_proj = (const float*)d_in[6];
  const float* b_proj = (const float*)d_in[7];
  float* out = (float*)d_out;

  float* ws        = (float*)d_ws;
  float* q_ws      = ws;
  float* kstep_ws  = ws + 8192;
  float* vstep_ws  = ws + 16384;
  float* y_ws      = ws + 24576;
  float* part_m    = ws + 32768;
  float* part_l    = ws + 34816;
  float* part_o    = ws + 36864;
  float* qkv_part  = ws + 167936;
  float* proj_part = ws + 561152;

  qkv_split_kernel<<<dim3(BB * 3 * KS1), dim3(256), 0, stream>>>(
      x, W_attn, qkv_part);
  qkv_reduce_kernel<<<dim3(96), dim3(256), 0, stream>>>(
      qkv_part, b_attn, q_ws, kstep_ws, vstep_ws, out);
  attn_partial_kernel<<<dim3(BB * HH * NS), dim3(256), 0, stream>>>(
      past_k, past_v, idx, q_ws, kstep_ws, vstep_ws, part_m, part_l, part_o);
  attn_combine_kernel<<<dim3(BB * HH), dim3(64), 0, stream>>>(
      part_m, part_l, part_o, y_ws);
  proj_split_kernel<<<dim3(BB * KS2), dim3(256), 0, stream>>>(
      y_ws, W_proj, proj_part);
  proj_reduce_kernel<<<dim3(32), dim3(256), 0, stream>>>(
      proj_part, b_proj, out);
}

// Round 2
// 510.333 us; speedup vs baseline: 1.1842x; 1.0585x over previous
//
#include <hip/hip_runtime.h>
#include <hip/hip_bf16.h>

#define BB 8
#define TT 8192
#define HH 16
#define HDIM 64
#define DDIM 1024
#define NS 16           /* splits per (b,h) */
#define TSPLIT 512      /* positions per split */
#define KS1 32          /* split-K for qkv GEMV (1024/32 rows each) */
#define KS2 32          /* split-K for proj GEMV (1024/32 rows each) */

// idx may arrive as int64 or int32; detect by high-word probe (values < 8192).
__device__ __forceinline__ int load_idx(const int* __restrict__ idx, int b) {
  const bool wide = (idx[1] == 0) && (idx[3] == 0) && (idx[5] == 0) && (idx[7] == 0);
  int v = wide ? idx[2 * b] : idx[b];
  return min(max(v, 0), TT - 1);   // defensive clamp: never OOB
}

// ---------------------------------------------------------------------------
// Kernel A1: split-K partial of qkv = x @ W_attn.
// grid = b(8) * jchunk(3) * ks(KS1) = 768 blocks, 256 threads.
// Each thread computes 4 adjacent outputs (float4 weight loads, fully
// coalesced: one wave reads 1 KB contiguous per dd row). K-slice = 32 rows.
// b-duplicates of the same W slice are 96 blocks apart; 96 % 8 == 0 so they
// land on the same XCD -> L2 hits for 7 of 8.
// ---------------------------------------------------------------------------
__global__ __launch_bounds__(256) void qkv_split_kernel(
    const float* __restrict__ x, const float* __restrict__ W,
    float* __restrict__ part)
{
  const int bid = blockIdx.x;
  const int ks = bid & (KS1 - 1);
  const int jc = (bid >> 5) % 3;
  const int b  = bid / (3 * KS1);
  const int tid = threadIdx.x;

  __shared__ float x_s[32];
  if (tid < 32) x_s[tid] = x[b * DDIM + ks * 32 + tid];
  __syncthreads();

  const int j0 = jc * 1024 + tid * 4;
  const float* wp = W + (size_t)(ks * 32) * 3072 + j0;
  float4 acc = {0.f, 0.f, 0.f, 0.f};
  #pragma unroll 8
  for (int dd = 0; dd < 32; ++dd) {
    float4 w4 = *(const float4*)(wp + (size_t)dd * 3072);
    const float xv = x_s[dd];
    acc.x += xv * w4.x; acc.y += xv * w4.y;
    acc.z += xv * w4.z; acc.w += xv * w4.w;
  }
  *(float4*)(part + (size_t)ks * (BB * 3072) + b * 3072 + j0) = acc;
}

// ---------------------------------------------------------------------------
// Kernel A2: reduce KS1 partials + bias; route to q_ws/kstep/vstep + out.
// 96 blocks x 256 (24576 outputs). All partials are L2/L3-resident.
// ---------------------------------------------------------------------------
__global__ __launch_bounds__(256) void qkv_reduce_kernel(
    const float* __restrict__ part, const float* __restrict__ bias,
    float* __restrict__ q_ws, float* __restrict__ kstep_ws,
    float* __restrict__ vstep_ws, float* __restrict__ out)
{
  const int g = blockIdx.x * 256 + threadIdx.x;   // 0..24575
  const int b = g / 3072;
  const int j = g % 3072;
  float acc = bias[j];
  #pragma unroll
  for (int ks = 0; ks < KS1; ++ks) acc += part[(size_t)ks * (BB * 3072) + g];

  if (j < 1024) {
    q_ws[b * DDIM + j] = acc * 0.125f;  // 1/sqrt(64)
  } else if (j < 2048) {
    const int jj = j - 1024;
    kstep_ws[b * DDIM + jj] = acc;
    out[8192 + b * DDIM + jj] = acc;    // output 1: k_step (fp32)
  } else {
    const int jj = j - 2048;
    vstep_ws[b * DDIM + jj] = acc;
    out[16384 + b * DDIM + jj] = acc;   // output 2: v_step (fp32)
  }
}

// ---------------------------------------------------------------------------
// Kernel B: flash-decode partial. Block = (b, h, split s) over TSPLIT=512
// positions for ONE head.
// Phase 1 is COALESCED: 4 lanes cooperate per K row (each lane reads 4
// float4s at 64B stride; a 4-lane group covers contiguous 64 B), then a
// 2-step __shfl_xor group reduce. A wave-instruction touches 16 fully-
// consumed cache lines instead of 64 partially-reused ones.
// Substitutes k_step/v_step at t == idx[b]; masks t > idx[b].
// Writes per-(b,h,s): m, l, o[64] (unnormalized).
// ---------------------------------------------------------------------------
__global__ __launch_bounds__(256) void attn_partial_kernel(
    const float* __restrict__ past_k, const float* __restrict__ past_v,
    const int* __restrict__ idx,
    const float* __restrict__ q_ws, const float* __restrict__ kstep_ws,
    const float* __restrict__ vstep_ws,
    float* __restrict__ part_m, float* __restrict__ part_l,
    float* __restrict__ part_o)
{
  const int tid = threadIdx.x;
  const int s  = blockIdx.x & (NS - 1);
  const int h  = (blockIdx.x >> 4) & (HH - 1);
  const int b  = blockIdx.x >> 8;
  const int idxb = load_idx(idx, b);
  const int t0 = s * TSPLIT;
  const int bhs = (b * HH + h) * NS + s;

  if (t0 > idxb) {   // whole split masked (uniform branch, before any barrier)
    if (tid == 0) { part_m[bhs] = -1e30f; part_l[bhs] = 0.f; }
    return;
  }
  const int nvalid = min(TSPLIT, idxb - t0 + 1);

  __shared__ float q_s[HDIM];
  __shared__ float p_s[TSPLIT];
  __shared__ float redm[8], redl[8];
  __shared__ float o_s[16 * HDIM];

  if (tid < HDIM) q_s[tid] = q_ws[b * DDIM + h * HDIM + tid];
  __syncthreads();                                   // barrier 1

  // ---- phase 1: scores, 4 lanes per row, 64 rows per round, 8 rounds ----
  const float* Kb = past_k + (((size_t)b * TT + t0) * HH + h) * HDIM;
  const float* krow_step = kstep_ws + b * DDIM + h * HDIM;
  const int rowg = tid >> 2;        // 0..63
  const int li   = tid & 3;         // lane within 4-lane row group
  #pragma unroll
  for (int r = 0; r < 8; ++r) {
    const int row = rowg + r * 64;  // 0..511
    float a = 0.f;
    if (row < nvalid) {
      const float* kr = (t0 + row == idxb)
                            ? krow_step
                            : (Kb + (size_t)row * (HH * HDIM));
      const float4* k4 = (const float4*)kr;
      float a0 = 0.f, a1 = 0.f, a2 = 0.f, a3 = 0.f;
      #pragma unroll
      for (int i = 0; i < 4; ++i) {
        const int q4 = li + i * 4;        // float4 index 0..15
        float4 u = k4[q4];
        const int d = q4 * 4;
        a0 += q_s[d + 0] * u.x;
        a1 += q_s[d + 1] * u.y;
        a2 += q_s[d + 2] * u.z;
        a3 += q_s[d + 3] * u.w;
      }
      a = (a0 + a1) + (a2 + a3);
    }
    a += __shfl_xor(a, 1, 64);
    a += __shfl_xor(a, 2, 64);
    if (li == 0) p_s[row] = (row < nvalid) ? a : -1e30f;
  }
  __syncthreads();                                   // barrier 2

  // ---- phase 2: block max (wave shuffle + 4-slot LDS), exp, block sum ----
  const float s0 = p_s[tid];
  const float s1 = p_s[tid + 256];
  float lmax = fmaxf(s0, s1);
  #pragma unroll
  for (int m = 32; m > 0; m >>= 1) lmax = fmaxf(lmax, __shfl_xor(lmax, m, 64));
  if ((tid & 63) == 0) redm[tid >> 6] = lmax;
  __syncthreads();                                   // barrier 3
  const float mh = fmaxf(fmaxf(redm[0], redm[1]), fmaxf(redm[2], redm[3]));

  // each thread overwrites exactly the two slots it read -> no barrier needed
  const float p0 = __expf(s0 - mh);   // masked rows: exp(-1e30 - mh) -> 0
  const float p1 = __expf(s1 - mh);
  p_s[tid] = p0;
  p_s[tid + 256] = p1;
  float lsum = p0 + p1;
  #pragma unroll
  for (int m = 32; m > 0; m >>= 1) lsum += __shfl_xor(lsum, m, 64);
  if ((tid & 63) == 0) redl[tid >> 6] = lsum;
  __syncthreads();                                   // barrier 4 (covers p_s)
  if (tid == 0) {
    part_m[bhs] = mh;
    part_l[bhs] = redl[0] + redl[1] + redl[2] + redl[3];
  }

  // ---- phase 3: o[d] = sum_t p[t]*V[t][d]; thread = (t-stripe, d-quad) ----
  const int tg = tid >> 4;          // 0..15  t-stripe
  const int d0 = (tid & 15) * 4;    // 0..60  d-quad
  const float* Vb = past_v + (((size_t)b * TT + t0) * HH + h) * HDIM + d0;
  const float* vrow_step = vstep_ws + b * DDIM + h * HDIM + d0;
  float a0 = 0.f, a1 = 0.f, a2 = 0.f, a3 = 0.f;
  for (int tl = tg; tl < nvalid; tl += 16) {
    const float p = p_s[tl];
    const float4 u = *(const float4*)((t0 + tl == idxb)
                                          ? vrow_step
                                          : (Vb + (size_t)tl * (HH * HDIM)));
    a0 += p * u.x; a1 += p * u.y; a2 += p * u.z; a3 += p * u.w;
  }
  o_s[tg * HDIM + d0 + 0] = a0;
  o_s[tg * HDIM + d0 + 1] = a1;
  o_s[tg * HDIM + d0 + 2] = a2;
  o_s[tg * HDIM + d0 + 3] = a3;
  __syncthreads();                                   // barrier 5
  if (tid < HDIM) {
    float acc = 0.f;
    #pragma unroll
    for (int g2 = 0; g2 < 16; ++g2) acc += o_s[g2 * HDIM + tid];
    part_o[(size_t)bhs * HDIM + tid] = acc;
  }
}

// ---------------------------------------------------------------------------
// Kernel D1: split-K partial of out_y = y @ W_proj, with the split-combine
// FUSED in: threads 0..31 reconstruct this block's 32-element y slice from
// the (L2-resident) attention partials, then all 256 threads do the GEMV.
// grid = b(8) * ks(KS2) = 256 blocks; thread = 4 outputs.
// ---------------------------------------------------------------------------
__global__ __launch_bounds__(256) void proj_split_kernel(
    const float* __restrict__ part_m, const float* __restrict__ part_l,
    const float* __restrict__ part_o,
    const float* __restrict__ W, float* __restrict__ part)
{
  const int bid = blockIdx.x;
  const int ks = bid & (KS2 - 1);
  const int b  = bid >> 5;
  const int tid = threadIdx.x;

  __shared__ float y_s[32];
  if (tid < 32) {
    const int h = ks >> 1;                 // y slice [ks*32, ks*32+32) lies
    const int d = (ks & 1) * 32 + tid;     // in head h, dims d..d (one each)
    const int bh = b * HH + h;
    float m[NS], l[NS];
    float M = -1e30f;
    #pragma unroll
    for (int s = 0; s < NS; ++s) {
      m[s] = part_m[bh * NS + s];
      l[s] = part_l[bh * NS + s];
      M = fmaxf(M, m[s]);
    }
    float L = 0.f, acc = 0.f;
    #pragma unroll
    for (int s = 0; s < NS; ++s) {
      float w = (l[s] > 0.f) ? __expf(m[s] - M) : 0.f;
      if (w > 0.f) {    // skip inactive splits: their part_o is poison
        L += l[s] * w;
        acc += w * part_o[(size_t)(bh * NS + s) * HDIM + d];
      }
    }
    y_s[tid] = (L > 0.f) ? (acc / L) : 0.f;
  }
  __syncthreads();

  const int j0 = tid * 4;
  const float* wp = W + (size_t)(ks * 32) * DDIM + j0;
  float4 acc = {0.f, 0.f, 0.f, 0.f};
  #pragma unroll 8
  for (int dd = 0; dd < 32; ++dd) {
    float4 w4 = *(const float4*)(wp + (size_t)dd * DDIM);
    const float yv = y_s[dd];
    acc.x += yv * w4.x; acc.y += yv * w4.y;
    acc.z += yv * w4.z; acc.w += yv * w4.w;
  }
  *(float4*)(part + (size_t)ks * (BB * DDIM) + b * DDIM + j0) = acc;
}

// ---------------------------------------------------------------------------
// Kernel D2: reduce KS2 proj partials + bias -> out[0..8192).
// 32 blocks x 256 (8192 outputs); partials are L2-resident.
// ---------------------------------------------------------------------------
__global__ __launch_bounds__(256) void proj_reduce_kernel(
    const float* __restrict__ part, const float* __restrict__ bias,
    float* __restrict__ out)
{
  const int g = blockIdx.x * 256 + threadIdx.x;   // 0..8191
  const int j = g & 1023;
  float acc = bias[j];
  #pragma unroll
  for (int ks = 0; ks < KS2; ++ks) acc += part[(size_t)ks * (BB * DDIM) + g];
  out[g] = acc;   // output 0: y (fp32)
}

// ---------------------------------------------------------------------------
// Workspace layout (floats): total = 1208320 floats = 4.83 MB
//   q_ws      [      0 ..    8192)
//   kstep_ws  [   8192 ..   16384)
//   vstep_ws  [  16384 ..   24576)
//   part_m    [  24576 ..   26624)   B*H*NS = 2048
//   part_l    [  26624 ..   28672)
//   part_o    [  28672 ..  159744)   B*H*NS*HDIM = 131072
//   qkv_part  [ 159744 ..  946176)   KS1 * 24576 = 786432
//   proj_part [ 946176 .. 1208320)   KS2 * 8192  = 262144
// ---------------------------------------------------------------------------
extern "C" void kernel_launch(void* const* d_in, const int* in_sizes, int n_in,
                              void* d_out, int out_size, void* d_ws, size_t ws_size,
                              hipStream_t stream) {
  const float* x      = (const float*)d_in[0];
  const float* past_k = (const float*)d_in[1];
  const float* past_v = (const float*)d_in[2];
  const int*   idx    = (const int*)  d_in[3];
  const float* W_attn = (const float*)d_in[4];
  const float* b_attn = (const float*)d_in[5];
  const float* W_proj = (const float*)d_in[6];
  const float* b_proj = (const float*)d_in[7];
  float* out = (float*)d_out;

  float* ws        = (float*)d_ws;
  float* q_ws      = ws;
  float* kstep_ws  = ws + 8192;
  float* vstep_ws  = ws + 16384;
  float* part_m    = ws + 24576;
  float* part_l    = ws + 26624;
  float* part_o    = ws + 28672;
  float* qkv_part  = ws + 159744;
  float* proj_part = ws + 946176;

  qkv_split_kernel<<<dim3(BB * 3 * KS1), dim3(256), 0, stream>>>(
      x, W_attn, qkv_part);
  qkv_reduce_kernel<<<dim3(96), dim3(256), 0, stream>>>(
      qkv_part, b_attn, q_ws, kstep_ws, vstep_ws, out);
  attn_partial_kernel<<<dim3(BB * HH * NS), dim3(256), 0, stream>>>(
      past_k, past_v, idx, q_ws, kstep_ws, vstep_ws, part_m, part_l, part_o);
  proj_split_kernel<<<dim3(BB * KS2), dim3(256), 0, stream>>>(
      part_m, part_l, part_o, W_proj, proj_part);
  proj_reduce_kernel<<<dim3(32), dim3(256), 0, stream>>>(
      proj_part, b_proj, out);
}